// Round 2
// baseline (13890.259 us; speedup 1.0000x reference)
//
#include <hip/hip_runtime.h>
#include <math.h>

#define RI __restrict__

namespace {

constexpr int Hn=512, En=512, Vn=10000, Fn=1280, Pn=196, Bn=32, Tn=80;
constexpr int KX = En + Fn;          // 1792
constexpr int G4 = 4*Hn;             // 2048
constexpr int NVT = 157;             // ceil(V/64)

// workspace layout (floats)
constexpr long O_ENC  = 0;                          // [B][P][H]
constexpr long O_W2T  = O_ENC  + (long)Bn*Pn*Hn;    // [F][H]
constexpr long O_W1T  = O_W2T  + (long)Fn*Hn;       // [H][H]   w1T[k][j] = W1[j][k]
constexpr long O_GWT  = O_W1T  + (long)Hn*Hn;       // [H][F]
constexpr long O_WHHT = O_GWT  + (long)Hn*Fn;       // [H][4H]
constexpr long O_WIHT = O_WHHT + (long)Hn*G4;       // [KX][4H]
constexpr long O_OWT  = O_WIHT + (long)KX*G4;       // [H][V]
constexpr long O_H    = O_OWT  + (long)Hn*Vn;       // [B][H]
constexpr long O_HT   = O_H    + (long)Bn*Hn;       // [H][B]
constexpr long O_C    = O_HT   + (long)Hn*Bn;       // [B][H]
constexpr long O_GATE = O_C    + (long)Bn*Hn;       // [B][F]
constexpr long O_CTX  = O_GATE + (long)Bn*Fn;       // [B][F]
constexpr long O_XP   = O_CTX  + (long)Bn*Fn;       // [B][4H]  whh*h + bih + bhh
constexpr long O_PMV  = O_XP   + (long)Bn*G4;       // [B][NVT]
constexpr long O_PMI  = O_PMV  + (long)Bn*NVT;      // [B][NVT] (int)

__device__ __forceinline__ float sigm(float x){ return 1.0f/(1.0f+expf(-x)); }
__device__ __forceinline__ void fma4(float4& a, const float4 w, const float x){
  a.x += w.x*x; a.y += w.y*x; a.z += w.z*x; a.w += w.w*x;
}

// ---------- generic tiled transpose: src[R][C] -> dst[C][R] ----------
__global__ __launch_bounds__(256) void k_tr(const float* RI src, float* RI dst, int R, int C){
  __shared__ float t[32][33];
  int tc0 = blockIdx.x*32, tr0 = blockIdx.y*32;
  int lx = threadIdx.x & 31, ly = threadIdx.x >> 5;
  for (int i = ly; i < 32; i += 8){
    int r = tr0 + i, c = tc0 + lx;
    t[i][lx] = (r < R && c < C) ? src[(long)r*C + c] : 0.f;
  }
  __syncthreads();
  for (int i = ly; i < 32; i += 8){
    int c = tc0 + i, r = tr0 + lx;
    if (c < C && r < R) dst[(long)c*R + r] = t[lx][i];
  }
}

// ---------- h0, c0 ----------
__global__ __launch_bounds__(256) void k_init(const float* RI feat,
    const float* RI ihw, const float* RI ihb, const float* RI icw, const float* RI icb,
    float* RI ws)
{
  __shared__ float mean[Fn];
  int b = blockIdx.x, tid = threadIdx.x;
  for (int f = tid; f < Fn; f += 256){
    const float* fp = feat + (long)b*Pn*Fn + f;
    float s = 0.f;
    for (int p = 0; p < Pn; ++p) s += fp[(long)p*Fn];
    mean[f] = s * (1.0f/Pn);
  }
  __syncthreads();
  for (int j = tid; j < Hn; j += 256){
    const float* wh = ihw + (long)j*Fn;
    const float* wc = icw + (long)j*Fn;
    float ah = ihb[j], ac = icb[j];
    for (int f = 0; f < Fn; f += 4){
      float4 w1 = *(const float4*)(wh+f);
      float4 w2 = *(const float4*)(wc+f);
      ah += w1.x*mean[f] + w1.y*mean[f+1] + w1.z*mean[f+2] + w1.w*mean[f+3];
      ac += w2.x*mean[f] + w2.y*mean[f+1] + w2.z*mean[f+2] + w2.w*mean[f+3];
    }
    ws[O_H + (long)b*Hn + j] = ah;
    ws[O_HT + (long)j*Bn + b] = ah;
    ws[O_C + (long)b*Hn + j] = ac;
  }
}

// ---------- enc_proj[b][p][j] = feat[b,p,:] @ W2T[:, j] + b2[j] ----------
// 784 blocks x 256 thr: 8 rows each; threads = 128 j-quads x 2 f-halves
__global__ __launch_bounds__(256) void k_encproj(const float* RI feat, const float* RI w2b,
                                                 float* RI ws)
{
  __shared__ __align__(16) float fsm[8*Fn];    // 40 KB, row-major
  int r0 = blockIdx.x*8, tid = threadIdx.x;
  for (int r = 0; r < 8; ++r)
    for (int f = tid; f < Fn; f += 256)
      fsm[r*Fn+f] = feat[(long)(r0+r)*Fn + f];
  __syncthreads();
  int q = tid & 127, sf = tid >> 7;
  int j4 = q*4;
  const float* wp = ws + O_W2T + j4;
  float4 acc[8];
  #pragma unroll
  for (int r = 0; r < 8; ++r) acc[r] = make_float4(0,0,0,0);
  for (int f = sf*640; f < sf*640+640; ++f){
    float4 w = *(const float4*)(wp + (long)f*Hn);
    #pragma unroll
    for (int r = 0; r < 8; ++r) fma4(acc[r], w, fsm[r*Fn+f]);
  }
  __syncthreads();
  float4* red = (float4*)fsm;
  if (sf == 1){
    #pragma unroll
    for (int r = 0; r < 8; ++r) red[q*8+r] = acc[r];
  }
  __syncthreads();
  if (sf == 0){
    float4 b4 = *(const float4*)(w2b + j4);
    #pragma unroll
    for (int r = 0; r < 8; ++r){
      float4 o = acc[r], p = red[q*8+r];
      o.x += p.x + b4.x; o.y += p.y + b4.y; o.z += p.z + b4.z; o.w += p.w + b4.w;
      *(float4*)(ws + O_ENC + (long)(r0+r)*Hn + j4) = o;
    }
  }
}

// ---------- phase A ----------
// blocks [0,32): attention per b (t<T)
// blocks [32,160): gate + whh*h (t<T)   128 blocks = 32 b x 4 quad-slices
// blocks [160,317): logits_{t-1} + partial argmax (t>=1)
// blocks [317,319): final h,c copy (t==T)
__global__ __launch_bounds__(256) void k_A(
    const float* RI feat, const float* RI w1b, const float* RI vaw, const float* RI vab,
    const float* RI bih, const float* RI bhh, const float* RI outb, const float* RI gb,
    float* RI ws, float* RI dout, int t)
{
  __shared__ __align__(16) float sm[2112];
  const int bb = blockIdx.x, tid = threadIdx.x;

  if (bb < 32){                       // ================ attention ================
    if (t >= Tn) return;
    const int b = bb;
    float* hl   = sm;          // 512
    float* hidl = sm + 512;    // 512
    float* aux  = sm + 1024;   // red2(1024) then sval(256)+wts(256)+inv
    for (int k = tid; k < Hn; k += 256) hl[k] = ws[O_H + (long)b*Hn + k];
    __syncthreads();
    // hid = h @ W1^T + b : threads = 128 j-quads x 2 k-halves
    {
      int q = tid & 127, kh = tid >> 7;
      int j4 = q*4;
      const float* wp = ws + O_W1T + j4;
      float4 a = make_float4(0,0,0,0);
      for (int k = kh*256; k < kh*256+256; k += 4){
        float4 w0 = *(const float4*)(wp + (long)(k+0)*Hn);
        float4 w1 = *(const float4*)(wp + (long)(k+1)*Hn);
        float4 w2 = *(const float4*)(wp + (long)(k+2)*Hn);
        float4 w3 = *(const float4*)(wp + (long)(k+3)*Hn);
        float4 h4 = *(const float4*)(hl + k);
        fma4(a, w0, h4.x); fma4(a, w1, h4.y); fma4(a, w2, h4.z); fma4(a, w3, h4.w);
      }
      *(float4*)(aux + kh*512 + j4) = a;
    }
    __syncthreads();
    for (int j = tid; j < Hn; j += 256)
      hidl[j] = aux[j] + aux[512+j] + w1b[j];
    __syncthreads();
    float* sval = aux;         // alias (red2 dead)
    float* wts  = aux + 256;
    float* invp = aux + 512;
    // scores: wave-per-p, lanes cover k
    {
      int w = tid >> 6, l = tid & 63;
      const float* eb = ws + O_ENC + (long)b*Pn*Hn;
      for (int p = w; p < Pn; p += 4){
        const float* er = eb + (long)p*Hn;
        float4 e0 = *(const float4*)(er + l*4);
        float4 e1 = *(const float4*)(er + 256 + l*4);
        float4 h0 = *(const float4*)(hidl + l*4);
        float4 h1 = *(const float4*)(hidl + 256 + l*4);
        float4 v0 = *(const float4*)(vaw + l*4);
        float4 v1 = *(const float4*)(vaw + 256 + l*4);
        float s = fmaxf(h0.x+e0.x,0.f)*v0.x + fmaxf(h0.y+e0.y,0.f)*v0.y
                + fmaxf(h0.z+e0.z,0.f)*v0.z + fmaxf(h0.w+e0.w,0.f)*v0.w
                + fmaxf(h1.x+e1.x,0.f)*v1.x + fmaxf(h1.y+e1.y,0.f)*v1.y
                + fmaxf(h1.z+e1.z,0.f)*v1.z + fmaxf(h1.w+e1.w,0.f)*v1.w;
        #pragma unroll
        for (int off = 32; off; off >>= 1) s += __shfl_down(s, off, 64);
        if (l == 0) sval[p] = s + vab[0];
      }
    }
    __syncthreads();
    if (tid < 64){                     // softmax stats on wave 0
      float m = -1e30f;
      for (int p = tid; p < Pn; p += 64) m = fmaxf(m, sval[p]);
      #pragma unroll
      for (int off = 32; off; off >>= 1) m = fmaxf(m, __shfl_xor(m, off, 64));
      float s = 0.f;
      for (int p = tid; p < Pn; p += 64){
        float e = expf(sval[p] - m);
        sval[p] = e;
        s += e;
      }
      #pragma unroll
      for (int off = 32; off; off >>= 1) s += __shfl_xor(s, off, 64);
      if (tid == 0) invp[0] = 1.0f/s;
    }
    __syncthreads();
    if (tid < Pn){
      float wv = sval[tid] * invp[0];
      wts[tid] = wv;
      dout[(long)Bn*Tn*Vn + 2L*Bn*Hn + ((long)b*Tn + t)*Pn + tid] = wv;
    }
    __syncthreads();
    // context: f-parallel coalesced
    {
      const float* fb = feat + (long)b*Pn*Fn;
      float4 a0 = make_float4(0,0,0,0), a1 = make_float4(0,0,0,0);
      for (int p = 0; p < Pn; ++p){
        float wv = wts[p];
        fma4(a0, *(const float4*)(fb + (long)p*Fn + tid*4), wv);
        if (tid < 64) fma4(a1, *(const float4*)(fb + (long)p*Fn + 1024 + tid*4), wv);
      }
      *(float4*)(ws + O_CTX + (long)b*Fn + tid*4) = a0;
      if (tid < 64) *(float4*)(ws + O_CTX + (long)b*Fn + 1024 + tid*4) = a1;
    }

  } else if (bb < 160){               // ================ gate + whh ================
    if (t >= Tn) return;
    int lb = bb - 32;
    int b = lb >> 2, qs = lb & 3;
    int qb = qs*256 + tid;            // [0,1024): 320 gate quads, 512 whh quads, rest idle
    const float* hb = ws + O_H + (long)b*Hn;
    if (qb < 320){
      int f4 = qb*4;
      const float* wp = ws + O_GWT + f4;
      float4 acc = make_float4(gb[f4], gb[f4+1], gb[f4+2], gb[f4+3]);
      for (int k = 0; k < Hn; k += 4){
        float4 h4 = *(const float4*)(hb + k);
        fma4(acc, *(const float4*)(wp + (long)(k+0)*Fn), h4.x);
        fma4(acc, *(const float4*)(wp + (long)(k+1)*Fn), h4.y);
        fma4(acc, *(const float4*)(wp + (long)(k+2)*Fn), h4.z);
        fma4(acc, *(const float4*)(wp + (long)(k+3)*Fn), h4.w);
      }
      acc.x = sigm(acc.x); acc.y = sigm(acc.y); acc.z = sigm(acc.z); acc.w = sigm(acc.w);
      *(float4*)(ws + O_GATE + (long)b*Fn + f4) = acc;
    } else if (qb < 832){
      int j4 = (qb - 320)*4;
      const float* wp = ws + O_WHHT + j4;
      float4 bi = *(const float4*)(bih + j4);
      float4 bh = *(const float4*)(bhh + j4);
      float4 acc = make_float4(bi.x+bh.x, bi.y+bh.y, bi.z+bh.z, bi.w+bh.w);
      for (int k = 0; k < Hn; k += 4){
        float4 h4 = *(const float4*)(hb + k);
        fma4(acc, *(const float4*)(wp + (long)(k+0)*G4), h4.x);
        fma4(acc, *(const float4*)(wp + (long)(k+1)*G4), h4.y);
        fma4(acc, *(const float4*)(wp + (long)(k+2)*G4), h4.z);
        fma4(acc, *(const float4*)(wp + (long)(k+3)*G4), h4.w);
      }
      *(float4*)(ws + O_XP + (long)b*G4 + j4) = acc;
    }

  } else if (bb < 317){               // ================ logits + partial argmax ================
    if (t == 0) return;
    int lb = bb - 160;                // 0..156
    int v0 = lb*64;
    int vl = tid & 63, bo = (tid >> 6)*8;
    int v = v0 + vl;
    int vc = (v < Vn) ? v : (Vn-1);
    const float* wt = ws + O_OWT + vc;
    const float* hT = ws + O_HT + bo;
    float a[8] = {0,0,0,0,0,0,0,0};
    for (int k = 0; k < Hn; k += 2){
      float w0 = wt[(long)(k+0)*Vn];
      float w1 = wt[(long)(k+1)*Vn];
      float4 ha0 = *(const float4*)(hT + (k+0)*Bn);
      float4 hb0 = *(const float4*)(hT + (k+0)*Bn + 4);
      float4 ha1 = *(const float4*)(hT + (k+1)*Bn);
      float4 hb1 = *(const float4*)(hT + (k+1)*Bn + 4);
      a[0]+=w0*ha0.x+w1*ha1.x; a[1]+=w0*ha0.y+w1*ha1.y;
      a[2]+=w0*ha0.z+w1*ha1.z; a[3]+=w0*ha0.w+w1*ha1.w;
      a[4]+=w0*hb0.x+w1*hb1.x; a[5]+=w0*hb0.y+w1*hb1.y;
      a[6]+=w0*hb0.z+w1*hb1.z; a[7]+=w0*hb0.w+w1*hb1.w;
    }
    float bias = outb[vc];
    float* rv = sm;                   // [32][64]
    if (v < Vn){
      #pragma unroll
      for (int i = 0; i < 8; ++i){
        float lv = a[i] + bias;
        dout[(long)(bo+i)*Tn*Vn + (long)(t-1)*Vn + v] = lv;
        rv[(bo+i)*64 + vl] = lv;
      }
    } else {
      #pragma unroll
      for (int i = 0; i < 8; ++i) rv[(bo+i)*64 + vl] = -1e30f;
    }
    __syncthreads();
    int bl = tid >> 3, e = tid & 7;
    float bv = -1e30f; int bi = 0x7fffffff;
    #pragma unroll
    for (int q = 0; q < 8; ++q){
      int vv = e*8 + q;
      float cv = rv[bl*64 + vv];
      if (cv > bv){ bv = cv; bi = vv; }
    }
    #pragma unroll
    for (int off = 4; off; off >>= 1){
      float ov = __shfl_down(bv, off, 8);
      int   oi = __shfl_down(bi, off, 8);
      if (ov > bv || (ov == bv && oi < bi)){ bv = ov; bi = oi; }
    }
    if (e == 0){
      ws[O_PMV + (long)bl*NVT + lb] = bv;
      ((int*)(ws + O_PMI))[(long)bl*NVT + lb] = v0 + bi;
    }

  } else {                            // ================ final h,c copy ================
    if (t != Tn) return;
    int g = bb - 317;
    const float* src = ws + (g == 0 ? O_H : O_C);
    float* dst = dout + (long)Bn*Tn*Vn + (long)g*Bn*Hn;
    for (int i = tid; i < Bn*Hn; i += 256) dst[i] = src[i];
  }
}

// ---------- phase B: argmax finalize, x build, Wih@x, LSTM update ----------
// 128 blocks = 4 b-groups x 32 i-slices (16 i). 256 thr = 16 (gate,quad) x 16 k-slices
__global__ __launch_bounds__(256) void k_B(const float* RI emb, float* RI ws, int t)
{
  __shared__ __align__(16) float xT[KX*8];    // [k][8 b], 57344 B; aliased as reduce buf
  __shared__ float gbuf[4*16*8];              // [gate][i_local][b]
  __shared__ int amax[8];
  const int bb = blockIdx.x, tid = threadIdx.x;
  const int bg = bb & 3, is = bb >> 2;
  const int b0 = bg*8, i0 = is*16;
  const int ql = tid & 15, sk = tid >> 4;
  const int gate = ql >> 2, qq = ql & 3;
  const int jbase = gate*Hn + i0 + qq*4;

  if (t > 0){
    int bl = tid >> 5, e = tid & 31;
    if (bl < 8){
      int b = b0 + bl;
      float bv = -1e30f; int bi = 0x7fffffff;
      for (int q = e; q < NVT; q += 32){
        float cv = ws[O_PMV + (long)b*NVT + q];
        if (cv > bv){ bv = cv; bi = ((const int*)(ws + O_PMI))[(long)b*NVT + q]; }
      }
      #pragma unroll
      for (int off = 16; off; off >>= 1){
        float ov = __shfl_down(bv, off, 32);
        int   oi = __shfl_down(bi, off, 32);
        if (ov > bv || (ov == bv && oi < bi)){ bv = ov; bi = oi; }
      }
      if (e == 0) amax[bl] = bi;
    }
  }
  __syncthreads();

  // stage x^T[k][bl]
  for (int idx = tid; idx < KX*8; idx += 256){
    int k = idx >> 3, bl = idx & 7;
    float x;
    if (k < En){
      int row = (t == 0) ? 1 : amax[bl];
      x = emb[(long)row*En + k];
    } else {
      int f = k - En;
      long o = (long)(b0+bl)*Fn + f;
      x = ws[O_CTX + o] * ws[O_GATE + o];
    }
    xT[idx] = x;
  }
  __syncthreads();

  const float* wp = ws + O_WIHT + jbase;
  float4 acc[8];
  #pragma unroll
  for (int i = 0; i < 8; ++i) acc[i] = make_float4(0,0,0,0);
  for (int k = sk*112; k < sk*112+112; ++k){
    float4 w  = *(const float4*)(wp + (long)k*G4);
    float4 xa = *(const float4*)(xT + k*8);
    float4 xb = *(const float4*)(xT + k*8 + 4);
    fma4(acc[0], w, xa.x); fma4(acc[1], w, xa.y); fma4(acc[2], w, xa.z); fma4(acc[3], w, xa.w);
    fma4(acc[4], w, xb.x); fma4(acc[5], w, xb.y); fma4(acc[6], w, xb.z); fma4(acc[7], w, xb.w);
  }
  __syncthreads();                    // xT reads done; alias as reduce buffer
  float4* red = (float4*)xT;
  #pragma unroll
  for (int off = 8; off >= 1; off >>= 1){
    if (sk >= off && sk < 2*off){
      int slot = (sk-off)*16 + ql;
      #pragma unroll
      for (int i = 0; i < 8; ++i) red[slot*8 + i] = acc[i];
    }
    __syncthreads();
    if (sk < off){
      int slot = sk*16 + ql;
      #pragma unroll
      for (int i = 0; i < 8; ++i){
        float4 p = red[slot*8 + i];
        acc[i].x += p.x; acc[i].y += p.y; acc[i].z += p.z; acc[i].w += p.w;
      }
    }
    __syncthreads();
  }
  if (sk == 0){
    #pragma unroll
    for (int bl = 0; bl < 8; ++bl){
      float4 xp = *(const float4*)(ws + O_XP + (long)(b0+bl)*G4 + jbase);
      gbuf[(gate*16 + qq*4 + 0)*8 + bl] = acc[bl].x + xp.x;
      gbuf[(gate*16 + qq*4 + 1)*8 + bl] = acc[bl].y + xp.y;
      gbuf[(gate*16 + qq*4 + 2)*8 + bl] = acc[bl].z + xp.z;
      gbuf[(gate*16 + qq*4 + 3)*8 + bl] = acc[bl].w + xp.w;
    }
  }
  __syncthreads();
  if (tid < 128){
    int il = tid >> 3, bl = tid & 7;
    int b = b0 + bl, i = i0 + il;
    float gi = gbuf[(0*16+il)*8 + bl];
    float gf = gbuf[(1*16+il)*8 + bl];
    float gg = gbuf[(2*16+il)*8 + bl];
    float go = gbuf[(3*16+il)*8 + bl];
    float co = ws[O_C + (long)b*Hn + i];
    float cn = sigm(gf)*co + sigm(gi)*tanhf(gg);
    float hn = sigm(go)*tanhf(cn);
    ws[O_C + (long)b*Hn + i] = cn;
    ws[O_H + (long)b*Hn + i] = hn;
    ws[O_HT + (long)i*Bn + b] = hn;
  }
}

} // anonymous namespace

extern "C" void kernel_launch(void* const* d_in, const int* in_sizes, int n_in,
                              void* d_out, int out_size, void* d_ws, size_t ws_size,
                              hipStream_t stream)
{
  (void)in_sizes; (void)n_in; (void)out_size; (void)ws_size;
  const float* feat = (const float*)d_in[0];
  const float* emb  = (const float*)d_in[3];
  const float* w1w  = (const float*)d_in[4];
  const float* w1b  = (const float*)d_in[5];
  const float* w2w  = (const float*)d_in[6];
  const float* w2b  = (const float*)d_in[7];
  const float* vaw  = (const float*)d_in[8];
  const float* vab  = (const float*)d_in[9];
  const float* wih  = (const float*)d_in[10];
  const float* whh  = (const float*)d_in[11];
  const float* bih  = (const float*)d_in[12];
  const float* bhh  = (const float*)d_in[13];
  const float* outw = (const float*)d_in[14];
  const float* outb = (const float*)d_in[15];
  const float* ihw  = (const float*)d_in[16];
  const float* ihb  = (const float*)d_in[17];
  const float* icw  = (const float*)d_in[18];
  const float* icb  = (const float*)d_in[19];
  const float* gw   = (const float*)d_in[20];
  const float* gb   = (const float*)d_in[21];
  float* ws  = (float*)d_ws;
  float* out = (float*)d_out;

  // one-time transposes (src[R][C] -> dst[C][R])
  k_tr<<<dim3(40,16),  dim3(256), 0, stream>>>(w2w,  ws + O_W2T,  Hn, Fn);   // [H][F]->[F][H]
  k_tr<<<dim3(16,16),  dim3(256), 0, stream>>>(w1w,  ws + O_W1T,  Hn, Hn);
  k_tr<<<dim3(16,40),  dim3(256), 0, stream>>>(gw,   ws + O_GWT,  Fn, Hn);   // [F][H]->[H][F]
  k_tr<<<dim3(16,64),  dim3(256), 0, stream>>>(whh,  ws + O_WHHT, G4, Hn);   // [4H][H]->[H][4H]
  k_tr<<<dim3(56,64),  dim3(256), 0, stream>>>(wih,  ws + O_WIHT, G4, KX);   // [4H][KX]->[KX][4H]
  k_tr<<<dim3(16,313), dim3(256), 0, stream>>>(outw, ws + O_OWT,  Vn, Hn);   // [V][H]->[H][V]

  k_init<<<dim3(32), dim3(256), 0, stream>>>(feat, ihw, ihb, icw, icb, ws);
  k_encproj<<<dim3(784), dim3(256), 0, stream>>>(feat, w2b, ws);

  for (int t = 0; t <= Tn; ++t){
    k_A<<<dim3(319), dim3(256), 0, stream>>>(feat, w1b, vaw, vab, bih, bhh, outb, gb,
                                             ws, out, t);
    if (t < Tn)
      k_B<<<dim3(128), dim3(256), 0, stream>>>(emb, ws, t);
  }
}

// Round 3
// 12160.710 us; speedup vs baseline: 1.1422x; 1.1422x over previous
//
#include <hip/hip_runtime.h>
#include <math.h>

#define RI __restrict__

namespace {

constexpr int Hn=512, En=512, Vn=10000, Fn=1280, Pn=196, Bn=32, Tn=80;
constexpr int G4 = 2048;             // 4H
constexpr int KX = 1792;             // E+F
constexpr int NCAT = 13888;          // 512 + 1280 + 2048 + 157*64
constexpr int NVT = 157;             // logit tiles of 64
// j-region starts inside WCAT
constexpr int J_GATE = 512, J_XP = 1792, J_LOG = 3840;

// ---- workspace layout (float indices) ----
constexpr long O_ENC  = 0;                           // [B*P][H] enc_proj (3,211,264)
constexpr long O_W2T  = O_ENC  + (long)Bn*Pn*Hn;     // [F][H]
constexpr long O_WCAT = O_W2T  + (long)Fn*Hn;        // [512][NCAT]  (w1T|gwT|whhT|owT)
constexpr long O_WIHT = O_WCAT + (long)Hn*NCAT;      // [KX][2048]
constexpr long O_H    = O_WIHT + (long)KX*G4;        // [B][H]
constexpr long O_HT   = O_H    + (long)Bn*Hn;        // [H][B]
constexpr long O_C    = O_HT   + (long)Hn*Bn;        // [B][H]
constexpr long O_HID  = O_C    + (long)Bn*Hn;        // [B][H]
constexpr long O_GT   = O_HID  + (long)Bn*Hn;        // [F][B]
constexpr long O_XPT  = O_GT   + (long)Fn*Bn;        // [2048][B]
constexpr long O_XT   = O_XPT  + (long)G4*Bn;        // [KX][B]
constexpr long O_WTS  = O_XT   + (long)KX*Bn;        // [B][196]
constexpr long O_PMV  = O_WTS  + (long)Bn*Pn;        // [B][157]
constexpr long O_PMI  = O_PMV  + (long)Bn*NVT;       // [B][157] int
constexpr long O_SEL  = O_PMI  + (long)Bn*NVT;       // [B] int
// setup-only aliases (inside O_ENC, consumed before k_encproj overwrites)
constexpr long O_IHCT  = O_ENC;                      // [1280][1024] (ihwT|icwT)
constexpr long O_MEANT = O_ENC + (long)Fn*1024;      // [F][B]

__device__ __forceinline__ float sigm(float x){ return 1.0f/(1.0f+expf(-x)); }
__device__ __forceinline__ void fma4(float4& a, const float4 x, const float w){
  a.x += w*x.x; a.y += w*x.y; a.z += w*x.z; a.w += w*x.w;
}

// ---------- transpose with dst stride: dst[c*S + r] = src[r*C + c] ----------
__global__ __launch_bounds__(256) void k_tr_s(const float* RI src, float* RI dst,
                                              int R, int C, int S){
  __shared__ float t[32][33];
  int tc0 = blockIdx.x*32, tr0 = blockIdx.y*32;
  int lx = threadIdx.x & 31, ly = threadIdx.x >> 5;
  for (int i = ly; i < 32; i += 8){
    int r = tr0 + i, c = tc0 + lx;
    t[i][lx] = (r < R && c < C) ? src[(long)r*C + c] : 0.f;
  }
  __syncthreads();
  for (int i = ly; i < 32; i += 8){
    int c = tc0 + i, r = tr0 + lx;
    if (c < C && r < R) dst[(long)c*S + r] = t[lx][i];
  }
}

// ---------- meanT[f][b] = mean_p feat[b,p,f] ----------
__global__ __launch_bounds__(256) void k_mean(const float* RI feat, float* RI ws){
  int blk = blockIdx.x;             // 160 = 32 b x 5 f-tiles
  int b = blk / 5, ft = blk % 5;
  int f = ft*256 + threadIdx.x;
  float s = 0.f;
  const float* fp = feat + (long)b*Pn*Fn + f;
  for (int p = 0; p < Pn; ++p) s += fp[(long)p*Fn];
  ws[O_MEANT + (long)f*Bn + b] = s * (1.0f/Pn);
}

// ---------- h0,c0 = mean @ [ihwT|icwT] + bias ----------
__global__ __launch_bounds__(512) void k_h0c0(const float* RI ihb, const float* RI icb,
                                              float* RI ws){
  int tid = threadIdx.x;
  int jl = tid & 63, bq = tid >> 6;          // 8 b-quads
  int j = blockIdx.x*64 + jl;                // [0,1024)
  const float* wp = ws + O_IHCT + j;
  const float* xp = ws + O_MEANT + bq*4;
  float4 acc = make_float4(0,0,0,0);
  for (int k = 0; k < Fn; ++k){
    float w = wp[(long)k*1024];
    float4 x = *(const float4*)(xp + (long)k*Bn);
    fma4(acc, x, w);
  }
  float va[4] = {acc.x, acc.y, acc.z, acc.w};
  if (j < Hn){
    float bias = ihb[j];
    #pragma unroll
    for (int m = 0; m < 4; ++m){
      int b = bq*4 + m;
      float v = va[m] + bias;
      ws[O_H  + (long)b*Hn + j] = v;
      ws[O_HT + (long)j*Bn + b] = v;
    }
  } else {
    int j2 = j - Hn;
    float bias = icb[j2];
    #pragma unroll
    for (int m = 0; m < 4; ++m)
      ws[O_C + (long)(bq*4+m)*Hn + j2] = va[m] + bias;
  }
}

// ---------- enc_proj = feat[6272x1280] @ W2T + b2 ----------
__global__ __launch_bounds__(512) void k_encproj(const float* RI feat, const float* RI w2b,
                                                 float* RI ws){
  __shared__ float ft[32*65];
  int rt = blockIdx.x >> 3, ct = blockIdx.x & 7;
  int r0 = rt*64, j0 = ct*64;
  int tid = threadIdx.x;
  int jl = tid & 63, ro = tid >> 6;
  int j = j0 + jl;
  float acc[8] = {0,0,0,0,0,0,0,0};
  const float* w2t = ws + O_W2T;
  for (int k0 = 0; k0 < Fn; k0 += 32){
    int lr = tid >> 3, kq = tid & 7;
    float4 v = *(const float4*)(feat + (long)(r0+lr)*Fn + k0 + kq*4);
    ft[(kq*4+0)*65 + lr] = v.x; ft[(kq*4+1)*65 + lr] = v.y;
    ft[(kq*4+2)*65 + lr] = v.z; ft[(kq*4+3)*65 + lr] = v.w;
    __syncthreads();
    for (int kk = 0; kk < 32; ++kk){
      float w = w2t[(long)(k0+kk)*Hn + j];
      const float* fb = ft + kk*65 + ro*8;
      #pragma unroll
      for (int m = 0; m < 8; ++m) acc[m] += w * fb[m];
    }
    __syncthreads();
  }
  float bias = w2b[j];
  #pragma unroll
  for (int m = 0; m < 8; ++m)
    ws[O_ENC + (long)(r0 + ro*8 + m)*Hn + j] = acc[m] + bias;
}

// ---------- K1: unified h-GEMM. 217 blocks x 512 thr ----------
// blocks [0,8): hid  [8,28): gate  [28,60): xpart  [60,217): logits_{t-1}+argmax
__global__ __launch_bounds__(512) void k_step1(
    const float* RI w1b, const float* RI gb, const float* RI bih, const float* RI bhh,
    const float* RI outb, float* RI ws, float* RI dout, int t)
{
  const int blk = blockIdx.x, tid = threadIdx.x;
  const int jl = tid & 63, bq = tid >> 6;
  if (blk < 60){
    if (t == Tn){                    // final h,c copy
      if (blk < 2){
        const float* src = ws + (blk == 0 ? O_H : O_C);
        float* dst = dout + (long)Bn*Tn*Vn + (long)blk*Bn*Hn;
        for (int i = tid; i < Bn*Hn; i += 512) dst[i] = src[i];
      }
      return;
    }
  } else {
    if (t == 0) return;
  }
  const int j = blk*64 + jl;
  const float* wp = ws + O_WCAT + j;
  const float* xp = ws + O_HT + bq*4;
  float4 acc = make_float4(0,0,0,0);
  #pragma unroll 4
  for (int k = 0; k < Hn; ++k){
    float w = wp[(long)k*NCAT];
    float4 x = *(const float4*)(xp + (k << 5));
    fma4(acc, x, w);
  }
  if (blk < 8){                      // hid
    float bias = w1b[j];
    ws[O_HID + (long)(bq*4+0)*Hn + j] = acc.x + bias;
    ws[O_HID + (long)(bq*4+1)*Hn + j] = acc.y + bias;
    ws[O_HID + (long)(bq*4+2)*Hn + j] = acc.z + bias;
    ws[O_HID + (long)(bq*4+3)*Hn + j] = acc.w + bias;
  } else if (blk < 28){              // gate (sigmoid)
    int f = j - J_GATE;
    float bias = gb[f];
    float4 g = make_float4(sigm(acc.x+bias), sigm(acc.y+bias),
                           sigm(acc.z+bias), sigm(acc.w+bias));
    *(float4*)(ws + O_GT + (long)f*Bn + bq*4) = g;
  } else if (blk < 60){              // xpart = whh@h + bih + bhh
    int j2 = j - J_XP;
    float bias = bih[j2] + bhh[j2];
    float4 a = make_float4(acc.x+bias, acc.y+bias, acc.z+bias, acc.w+bias);
    *(float4*)(ws + O_XPT + (long)j2*Bn + bq*4) = a;
  } else {                           // logits + per-tile argmax partials
    int v = j - J_LOG;
    float lv[4];
    if (v < Vn){
      float bias = outb[v];
      lv[0]=acc.x+bias; lv[1]=acc.y+bias; lv[2]=acc.z+bias; lv[3]=acc.w+bias;
      #pragma unroll
      for (int m = 0; m < 4; ++m)
        dout[((long)(bq*4+m)*Tn + (t-1))*Vn + v] = lv[m];
    } else {
      lv[0]=lv[1]=lv[2]=lv[3]=-1e30f;
    }
    int tile = blk - 60;
    #pragma unroll
    for (int m = 0; m < 4; ++m){
      float bv = lv[m]; int bi = v;
      #pragma unroll
      for (int off = 32; off; off >>= 1){
        float ov = __shfl_down(bv, off, 64);
        int   oi = __shfl_down(bi, off, 64);
        if (ov > bv || (ov == bv && oi < bi)){ bv = ov; bi = oi; }
      }
      if (jl == 0){
        int b = bq*4 + m;
        ws[O_PMV + (long)b*NVT + tile] = bv;
        ((int*)(ws + O_PMI))[(long)b*NVT + tile] = bi;
      }
    }
  }
}

// ---------- K2: scores+softmax per b (32 blocks) + argmax finalize (block 32) ----------
__global__ __launch_bounds__(256) void k_attn(const float* RI vaw, const float* RI vab,
                                              float* RI ws, float* RI dout, int t)
{
  __shared__ float hid_s[512];
  __shared__ float sval[256];
  __shared__ float inv_s;
  const int bb = blockIdx.x, tid = threadIdx.x;
  if (bb < 32){
    const int b = bb;
    for (int k = tid; k < Hn; k += 256) hid_s[k] = ws[O_HID + (long)b*Hn + k];
    __syncthreads();
    {
      int w = tid >> 6, l = tid & 63;
      const float* eb = ws + O_ENC + (long)b*Pn*Hn;
      for (int p = w; p < Pn; p += 4){
        const float* er = eb + (long)p*Hn;
        float4 e0 = *(const float4*)(er + l*4);
        float4 e1 = *(const float4*)(er + 256 + l*4);
        float4 h0 = *(const float4*)(hid_s + l*4);
        float4 h1 = *(const float4*)(hid_s + 256 + l*4);
        float4 v0 = *(const float4*)(vaw + l*4);
        float4 v1 = *(const float4*)(vaw + 256 + l*4);
        float s = fmaxf(h0.x+e0.x,0.f)*v0.x + fmaxf(h0.y+e0.y,0.f)*v0.y
                + fmaxf(h0.z+e0.z,0.f)*v0.z + fmaxf(h0.w+e0.w,0.f)*v0.w
                + fmaxf(h1.x+e1.x,0.f)*v1.x + fmaxf(h1.y+e1.y,0.f)*v1.y
                + fmaxf(h1.z+e1.z,0.f)*v1.z + fmaxf(h1.w+e1.w,0.f)*v1.w;
        #pragma unroll
        for (int off = 32; off; off >>= 1) s += __shfl_down(s, off, 64);
        if (l == 0) sval[p] = s + vab[0];
      }
    }
    __syncthreads();
    if (tid < 64){
      float m = -1e30f;
      for (int p = tid; p < Pn; p += 64) m = fmaxf(m, sval[p]);
      #pragma unroll
      for (int off = 32; off; off >>= 1) m = fmaxf(m, __shfl_xor(m, off, 64));
      float s = 0.f;
      for (int p = tid; p < Pn; p += 64){
        float e = expf(sval[p] - m);
        sval[p] = e; s += e;
      }
      #pragma unroll
      for (int off = 32; off; off >>= 1) s += __shfl_xor(s, off, 64);
      if (tid == 0) inv_s = 1.0f/s;
    }
    __syncthreads();
    if (tid < Pn){
      float wv = sval[tid] * inv_s;
      ws[O_WTS + (long)b*Pn + tid] = wv;
      dout[(long)Bn*Tn*Vn + 2L*Bn*Hn + ((long)b*Tn + t)*Pn + tid] = wv;
    }
  } else {
    if (t == 0) return;
    int bl = tid >> 3, e = tid & 7;       // 32 b x 8 lanes
    float bv = -1e30f; int bi = 0x7fffffff;
    for (int q = e; q < NVT; q += 8){
      float cv = ws[O_PMV + (long)bl*NVT + q];
      if (cv > bv){ bv = cv; bi = ((const int*)(ws + O_PMI))[(long)bl*NVT + q]; }
    }
    #pragma unroll
    for (int off = 4; off; off >>= 1){
      float ov = __shfl_down(bv, off, 8);
      int   oi = __shfl_down(bi, off, 8);
      if (ov > bv || (ov == bv && oi < bi)){ bv = ov; bi = oi; }
    }
    if (e == 0) ((int*)(ws + O_SEL))[bl] = bi;
  }
}

// ---------- K3: ctx (x gate) + emb gather -> xT[k][b] ----------
// blocks [0,160): (b, f-tile 256) ctx;  [160,192): emb row gather per b
__global__ __launch_bounds__(256) void k_ctx(const float* RI feat, const float* RI emb,
                                             float* RI ws, int t)
{
  __shared__ float wl[Pn];
  const int blk = blockIdx.x, tid = threadIdx.x;
  if (blk < 160){
    int b = blk / 5, ft = blk % 5;
    if (tid < Pn) wl[tid] = ws[O_WTS + (long)b*Pn + tid];
    __syncthreads();
    int f = ft*256 + tid;
    const float* fp = feat + (long)b*Pn*Fn + f;
    float a = 0.f;
    for (int p = 0; p < Pn; ++p) a += wl[p] * fp[(long)p*Fn];
    a *= ws[O_GT + (long)f*Bn + b];
    ws[O_XT + (long)(En + f)*Bn + b] = a;
  } else {
    int b = blk - 160;
    int row = (t == 0) ? 1 : ((const int*)(ws + O_SEL))[b];
    const float* er = emb + (long)row*En;
    for (int k = tid; k < En; k += 256)
      ws[O_XT + (long)k*Bn + b] = er[k];
  }
}

// ---------- K4: gates = Wih@x + xpart; LSTM update. 128 blocks x 256 thr ----------
__global__ __launch_bounds__(256) void k_gates(float* RI ws, int t)
{
  __shared__ float red[4*16*32];   // 8 KB
  __shared__ float gbuf[16*32];
  const int blk = blockIdx.x, tid = threadIdx.x;
  const int i0 = blk*4;
  const int sk = tid >> 6, lane = tid & 63;
  const int jj = lane & 15, bo = lane >> 4;
  const int g = jj >> 2, il = jj & 3;
  const int j = g*Hn + i0 + il;
  const float* wp = ws + O_WIHT + j;
  const float* xb = ws + O_XT + bo*8;
  float4 a0 = make_float4(0,0,0,0), a1 = make_float4(0,0,0,0);
  const int kb = sk*448;
  for (int k = kb; k < kb + 448; ++k){
    float w = wp[(long)k*G4];
    float4 x0 = *(const float4*)(xb + (long)k*Bn);
    float4 x1 = *(const float4*)(xb + (long)k*Bn + 4);
    fma4(a0, x0, w); fma4(a1, x1, w);
  }
  {
    float* rb = red + ((sk*16 + jj)*32 + bo*8);
    *(float4*)(rb) = a0; *(float4*)(rb + 4) = a1;
  }
  __syncthreads();
  if (tid < 128){
    int jj2 = tid >> 3, bq = tid & 7;
    float4 s = make_float4(0,0,0,0);
    #pragma unroll
    for (int sk2 = 0; sk2 < 4; ++sk2){
      float4 p = *(const float4*)(red + ((sk2*16 + jj2)*32 + bq*4));
      s.x += p.x; s.y += p.y; s.z += p.z; s.w += p.w;
    }
    int g2 = jj2 >> 2, il2 = jj2 & 3;
    int j2 = g2*Hn + i0 + il2;
    float4 xp = *(const float4*)(ws + O_XPT + (long)j2*Bn + bq*4);
    s.x += xp.x; s.y += xp.y; s.z += xp.z; s.w += xp.w;
    *(float4*)(gbuf + jj2*32 + bq*4) = s;
  }
  __syncthreads();
  if (tid < 128){
    int il3 = tid >> 5, b = tid & 31;
    int i = i0 + il3;
    float gi = gbuf[( 0 + il3)*32 + b];
    float gf = gbuf[( 4 + il3)*32 + b];
    float gg = gbuf[( 8 + il3)*32 + b];
    float go = gbuf[(12 + il3)*32 + b];
    float c  = ws[O_C + (long)b*Hn + i];
    float cn = sigm(gf)*c + sigm(gi)*tanhf(gg);
    float hn = sigm(go)*tanhf(cn);
    ws[O_C  + (long)b*Hn + i] = cn;
    ws[O_H  + (long)b*Hn + i] = hn;
    ws[O_HT + (long)i*Bn + b] = hn;
  }
}

} // anonymous namespace

extern "C" void kernel_launch(void* const* d_in, const int* in_sizes, int n_in,
                              void* d_out, int out_size, void* d_ws, size_t ws_size,
                              hipStream_t stream)
{
  (void)in_sizes; (void)n_in; (void)out_size; (void)ws_size;
  const float* feat = (const float*)d_in[0];
  const float* emb  = (const float*)d_in[3];
  const float* w1w  = (const float*)d_in[4];
  const float* w1b  = (const float*)d_in[5];
  const float* w2w  = (const float*)d_in[6];
  const float* w2b  = (const float*)d_in[7];
  const float* vaw  = (const float*)d_in[8];
  const float* vab  = (const float*)d_in[9];
  const float* wih  = (const float*)d_in[10];
  const float* whh  = (const float*)d_in[11];
  const float* bih  = (const float*)d_in[12];
  const float* bhh  = (const float*)d_in[13];
  const float* outw = (const float*)d_in[14];
  const float* outb = (const float*)d_in[15];
  const float* ihw  = (const float*)d_in[16];
  const float* ihb  = (const float*)d_in[17];
  const float* icw  = (const float*)d_in[18];
  const float* icb  = (const float*)d_in[19];
  const float* gw   = (const float*)d_in[20];
  const float* gb   = (const float*)d_in[21];
  float* ws  = (float*)d_ws;
  float* out = (float*)d_out;

  // setup-only transposes of ihw/icw into the ENC alias (consumed before encproj)
  k_tr_s<<<dim3(40,16),  256, 0, stream>>>(ihw,  ws + O_IHCT,       Hn, Fn, 1024);
  k_tr_s<<<dim3(40,16),  256, 0, stream>>>(icw,  ws + O_IHCT + 512, Hn, Fn, 1024);
  k_mean<<<160, 256, 0, stream>>>(feat, ws);
  k_h0c0<<<16, 512, 0, stream>>>(ihb, icb, ws);
  // persistent weight transposes
  k_tr_s<<<dim3(16,16),  256, 0, stream>>>(w1w,  ws + O_WCAT,          Hn, Hn, NCAT);
  k_tr_s<<<dim3(16,40),  256, 0, stream>>>(gw,   ws + O_WCAT + J_GATE, Fn, Hn, NCAT);
  k_tr_s<<<dim3(16,64),  256, 0, stream>>>(whh,  ws + O_WCAT + J_XP,   G4, Hn, NCAT);
  k_tr_s<<<dim3(16,313), 256, 0, stream>>>(outw, ws + O_WCAT + J_LOG,  Vn, Hn, NCAT);
  k_tr_s<<<dim3(56,64),  256, 0, stream>>>(wih,  ws + O_WIHT,          G4, KX, G4);
  k_tr_s<<<dim3(40,16),  256, 0, stream>>>(w2w,  ws + O_W2T,           Hn, Fn, Hn);
  k_encproj<<<784, 512, 0, stream>>>(feat, w2b, ws);

  for (int t = 0; t < Tn; ++t){
    k_step1<<<217, 512, 0, stream>>>(w1b, gb, bih, bhh, outb, ws, out, t);
    k_attn <<< 33, 256, 0, stream>>>(vaw, vab, ws, out, t);
    k_ctx  <<<192, 256, 0, stream>>>(feat, emb, ws, t);
    k_gates<<<128, 256, 0, stream>>>(ws, t);
  }
  k_step1<<<217, 512, 0, stream>>>(w1b, gb, bih, bhh, outb, ws, out, Tn);
}